// Round 5
// baseline (14844.606 us; speedup 1.0000x reference)
//
#include <hip/hip_runtime.h>

// 2-layer LSTM (H=256, T=256, B=512, I=2) + linear head.
// 256 blocks x 1024 threads, 2 batch elements per block, t-loop in-kernel.
// Weight stream fp16, thread tid owns gate-row j=tid (no duplication).
// 96 chunks of 16 KB per step; 84 streamed from L2 (4-deep register
// pipeline, wraps across layers/steps), 12 REGISTER-RESIDENT (one per 8,
// interleaved so the VMEM pipe never bubbles). Stream re-ordered by prep:
// streamed chunks contiguous [0..84), register chunks at tail [84..96).
// h in LDS fp16 (broadcast b128 reads), c in registers, 4 barriers/step.
// Gates via v_dot2_f32_f16. No cross-block traffic (round-3 lesson).

typedef float vf2 __attribute__((ext_vector_type(2)));
typedef _Float16 vh2 __attribute__((ext_vector_type(2)));
typedef _Float16 vh4 __attribute__((ext_vector_type(4)));
typedef _Float16 vh8 __attribute__((ext_vector_type(8)));

#define NT 1024
#define TSTEPS 256
#define CHB 16384         // bytes per chunk = 1024 threads * 16 B
#define NSTRM 84          // streamed chunks per step
#define NREG 12           // register-resident chunks
#define FS 393216         // fp32 table offset (floats) = 96*CHB/4

__global__ void prep_kernel(const float* __restrict__ W_ih1,
                            const float* __restrict__ W_hh1,
                            const float* __restrict__ b_ih1,
                            const float* __restrict__ b_hh1,
                            const float* __restrict__ W_ih2,
                            const float* __restrict__ W_hh2,
                            const float* __restrict__ b_ih2,
                            const float* __restrict__ b_hh2,
                            void* __restrict__ ws) {
    const int stride = gridDim.x * blockDim.x;
    const int idx = blockIdx.x * blockDim.x + threadIdx.x;
    _Float16* wh = (_Float16*)ws;
    float* wf = (float*)ws;
    // logical chunk ch (0..95) covers k = 8*ch..8*ch+7 for all 1024 rows.
    // k<256: W_hh1 | k<512: W_ih2 | else W_hh2.
    // placement: ch%8==3 -> register region pos = 84 + ch/8
    //            else    -> stream region  pos = ch - ch/8 - (ch%8>3)
    for (int e = idx; e < 96 * 8192; e += stride) {
        int ch = e >> 13, rem = e & 8191, row = rem >> 3, i = rem & 7;
        int k = (ch << 3) + i;
        float v;
        if (k < 256)      v = W_hh1[row * 256 + k];
        else if (k < 512) v = W_ih2[row * 256 + (k - 256)];
        else              v = W_hh2[row * 256 + (k - 512)];
        int pos;
        if ((ch & 7) == 3) pos = NSTRM + (ch >> 3);
        else               pos = ch - (ch >> 3) - (((ch & 7) > 3) ? 1 : 0);
        wh[pos * 8192 + rem] = (_Float16)v;
    }
    for (int j = idx; j < 1024; j += stride) {
        wf[FS + j]        = W_ih1[j * 2 + 0];
        wf[FS + 1024 + j] = W_ih1[j * 2 + 1];
        wf[FS + 2048 + j] = b_ih1[j] + b_hh1[j];
        wf[FS + 3072 + j] = b_ih2[j] + b_hh2[j];
    }
}

__device__ __forceinline__ float sig_(float v) {
    return 1.f / (1.f + __expf(-v));
}
__device__ __forceinline__ float tanh_(float v) {
    return 1.f - 2.f / (__expf(2.f * v) + 1.f);
}
__device__ __forceinline__ float fdot2_(vh2 a, vh2 b, float c) {
#if __has_builtin(__builtin_amdgcn_fdot2)
    return __builtin_amdgcn_fdot2(a, b, c, false);
#else
    return c + (float)a.x * (float)b.x + (float)a.y * (float)b.y;
#endif
}

// one 8-chunk group: 7 streamed (buffers X0..X6, reload after use) + 1
// register-resident chunk (slot 3). KB = local h base index for slot 0.
#define GRP(X0,X1,X2,X3,X4,X5,X6,RW,KB,HP)                              \
    usec(X0, HP, (KB));      loadc(X0);                                 \
    usec(X1, HP, (KB) + 8);  loadc(X1);                                 \
    usec(X2, HP, (KB) + 16); loadc(X2);                                 \
    usec(RW, HP, (KB) + 24);                                            \
    usec(X3, HP, (KB) + 32); loadc(X3);                                 \
    usec(X4, HP, (KB) + 40); loadc(X4);                                 \
    usec(X5, HP, (KB) + 48); loadc(X5);                                 \
    usec(X6, HP, (KB) + 56); loadc(X6);

// one layer-section: 4 groups (32 chunks, 256 k). 28 streamed chunks
// (28 % 4 == 0 -> buffer rotation realigns at section end).
#define LAYER(HP, R0)                                                   \
    GRP(bA,bB,bC,bD,bA,bB,bC, wreg[(R0)+0], 0,   HP)                    \
    GRP(bD,bA,bB,bC,bD,bA,bB, wreg[(R0)+1], 64,  HP)                    \
    GRP(bC,bD,bA,bB,bC,bD,bA, wreg[(R0)+2], 128, HP)                    \
    GRP(bB,bC,bD,bA,bB,bC,bD, wreg[(R0)+3], 192, HP)

__global__ __launch_bounds__(NT) void lstm_kernel(
    const float* __restrict__ x,      // (512, 256, 2)
    const void* __restrict__ ws,
    const float* __restrict__ W_lin,  // (2, 256)
    const float* __restrict__ b_lin,  // (2,)
    float* __restrict__ out)          // (512, 256, 2)
{
    __shared__ float gbuf[2][1024];        // gate preacts [batch][gate-row]
    __shared__ _Float16 hl1[2][2][256];    // h1 [parity][batch][unit]
    __shared__ _Float16 hl2[2][2][256];    // h2

    const int tid = threadIdx.x;
    const int j = tid;                     // owned gate-row
    const int u = tid & 255, bu = (tid >> 8) & 1;
    const int b0 = blockIdx.x * 2;
    const char* wstream = (const char*)ws;
    const float* wf = (const float*)ws;

    const float wx0 = wf[FS + j], wx1 = wf[FS + 1024 + j];
    const float bj1 = wf[FS + 2048 + j], bj2 = wf[FS + 3072 + j];

    // y-head: waves 0..3 -> (batch ob, output oo); lane covers 4 units
    const int lane = tid & 63, wv = tid >> 6;
    const int ob = (wv >> 1) & 1, oo = wv & 1;
    const float wl0 = W_lin[oo * 256 + 4 * lane + 0];
    const float wl1 = W_lin[oo * 256 + 4 * lane + 1];
    const float wl2 = W_lin[oo * 256 + 4 * lane + 2];
    const float wl3 = W_lin[oo * 256 + 4 * lane + 3];
    const float blin = b_lin[oo];

    for (int i = tid; i < 2 * 2 * 256; i += NT) {
        ((_Float16*)hl1)[i] = (_Float16)0.f;
        ((_Float16*)hl2)[i] = (_Float16)0.f;
    }

    float c1 = 0.f, c2 = 0.f;
    vf2 xv0 = *(const vf2*)(x + (size_t)(b0 + 0) * 512);
    vf2 xv1 = *(const vf2*)(x + (size_t)(b0 + 1) * 512);

    const int t16 = tid * 16;
    int sp = 0;                            // uniform stream byte offset
    float acc0, acc1;

    auto loadc = [&](vh8& dst) {
        dst = *(const vh8*)(wstream + sp + t16);
        sp += CHB;
        if (sp == NSTRM * CHB) sp = 0;
    };
    auto usec = [&](const vh8 w, const _Float16 (*hp)[256], int k0) {
        vh2 w0 = {w[0], w[1]}, w1 = {w[2], w[3]};
        vh2 w2 = {w[4], w[5]}, w3 = {w[6], w[7]};
        vh8 ha = *(const vh8*)&hp[0][k0];
        vh8 hb = *(const vh8*)&hp[1][k0];
        vh2 a0 = {ha[0], ha[1]}, a1 = {ha[2], ha[3]};
        vh2 a2 = {ha[4], ha[5]}, a3 = {ha[6], ha[7]};
        vh2 e0 = {hb[0], hb[1]}, e1 = {hb[2], hb[3]};
        vh2 e2 = {hb[4], hb[5]}, e3 = {hb[6], hb[7]};
        acc0 = fdot2_(w0, a0, acc0); acc0 = fdot2_(w1, a1, acc0);
        acc0 = fdot2_(w2, a2, acc0); acc0 = fdot2_(w3, a3, acc0);
        acc1 = fdot2_(w0, e0, acc1); acc1 = fdot2_(w1, e1, acc1);
        acc1 = fdot2_(w2, e2, acc1); acc1 = fdot2_(w3, e3, acc1);
    };

    // register-resident chunks (loaded once, reused all 256 steps)
    vh8 wreg[NREG];
    #pragma unroll
    for (int r = 0; r < NREG; ++r)
        wreg[r] = *(const vh8*)(wstream + (NSTRM + r) * CHB + t16);

    vh8 bA, bB, bC, bD;
    loadc(bA); loadc(bB); loadc(bC); loadc(bD);
    __syncthreads();

    #pragma unroll 1
    for (int t = 0; t < TSTEPS; ++t) {
        const int p = t & 1, pm = p ^ 1;

        // ---- layer 1 gates: b1 + Wih1*x_t + Whh1*h1(t-1) ----
        acc0 = bj1 + wx0 * xv0.x + wx1 * xv0.y;
        acc1 = bj1 + wx0 * xv1.x + wx1 * xv1.y;
        LAYER(hl1[pm], 0)
        gbuf[0][j] = acc0; gbuf[1][j] = acc1;
        __syncthreads();

        // ---- layer 1 cell update (threads 0..511: unit u, batch bu) ----
        if (tid < 512) {
            float gi = sig_(gbuf[bu][u]);
            float gf = sig_(gbuf[bu][256 + u]);
            float gg = tanh_(gbuf[bu][512 + u]);
            float go = sig_(gbuf[bu][768 + u]);
            c1 = gf * c1 + gi * gg;
            hl1[p][bu][u] = (_Float16)(go * tanh_(c1));
        }
        __syncthreads();

        // ---- layer 2 gates: b2 + Wih2*h1(t) + Whh2*h2(t-1) ----
        acc0 = bj2; acc1 = bj2;
        LAYER(hl1[p], 4)
        LAYER(hl2[pm], 8)
        gbuf[0][j] = acc0; gbuf[1][j] = acc1;
        __syncthreads();

        // ---- layer 2 cell update ----
        if (tid < 512) {
            float gi = sig_(gbuf[bu][u]);
            float gf = sig_(gbuf[bu][256 + u]);
            float gg = tanh_(gbuf[bu][512 + u]);
            float go = sig_(gbuf[bu][768 + u]);
            c2 = gf * c2 + gi * gg;
            hl2[p][bu][u] = (_Float16)(go * tanh_(c2));
        }
        __syncthreads();

        // ---- y = h2 @ W_lin.T + b_lin (waves 0..3) ----
        if (wv < 4) {
            vh4 hv = *(const vh4*)&hl2[p][ob][4 * lane];
            float s = (float)hv.x * wl0 + (float)hv.y * wl1
                    + (float)hv.z * wl2 + (float)hv.w * wl3;
            #pragma unroll
            for (int m = 32; m >= 1; m >>= 1) s += __shfl_xor(s, m, 64);
            if (lane == 0)
                out[(size_t)(b0 + ob) * 512 + t * 2 + oo] = s + blin;
        }

        // prefetch x for t+1 (wraps harmlessly at the end)
        const int tn = (t + 1) & (TSTEPS - 1);
        xv0 = *(const vf2*)(x + (size_t)(b0 + 0) * 512 + tn * 2);
        xv1 = *(const vf2*)(x + (size_t)(b0 + 1) * 512 + tn * 2);
    }
}

extern "C" void kernel_launch(void* const* d_in, const int* in_sizes, int n_in,
                              void* d_out, int out_size, void* d_ws, size_t ws_size,
                              hipStream_t stream) {
    const float* x     = (const float*)d_in[0];
    const float* W_ih1 = (const float*)d_in[1];
    const float* W_hh1 = (const float*)d_in[2];
    const float* b_ih1 = (const float*)d_in[3];
    const float* b_hh1 = (const float*)d_in[4];
    const float* W_ih2 = (const float*)d_in[5];
    const float* W_hh2 = (const float*)d_in[6];
    const float* b_ih2 = (const float*)d_in[7];
    const float* b_hh2 = (const float*)d_in[8];
    const float* W_lin = (const float*)d_in[9];
    const float* b_lin = (const float*)d_in[10];
    float* out = (float*)d_out;

    prep_kernel<<<256, 256, 0, stream>>>(W_ih1, W_hh1, b_ih1, b_hh1,
                                         W_ih2, W_hh2, b_ih2, b_hh2, d_ws);
    lstm_kernel<<<256, NT, 0, stream>>>(x, d_ws, W_lin, b_lin, out);
}

// Round 6
// 3518.505 us; speedup vs baseline: 4.2190x; 4.2190x over previous
//
#include <hip/hip_runtime.h>

// 2-layer LSTM (H=256, T=256, B=512, I=2) + linear head.
// 256 blocks x 1024 threads (1 block/CU pinned via __launch_bounds__),
// 2 batch elements per block, t-loop in-kernel.
// Weight stream fp16 (96 x 16KB chunks/step, L2-resident, no duplication:
// thread tid owns gate-row j=tid for both batches). Gates via
// v_dot2_f32_f16. h in LDS fp16 (wave-broadcast b128 reads), c in regs,
// 4 barriers/step, 4-deep register pipeline wrapping across layers/steps.
// Round-3 lesson: no cross-block exchange. Round-5 lesson: no big register
// arrays without an explicit launch-bounds occupancy contract (spills ->
// scratch -> L2 thrash: FETCH 39 GB, WRITE 930 MB).

typedef float vf2 __attribute__((ext_vector_type(2)));
typedef _Float16 vh2 __attribute__((ext_vector_type(2)));
typedef _Float16 vh4 __attribute__((ext_vector_type(4)));
typedef _Float16 vh8 __attribute__((ext_vector_type(8)));

#define NT 1024
#define TSTEPS 256
#define NCH 96            // chunks per step; chunk = 8 k-values x 1024 rows
#define CHB 16384         // bytes per chunk = 1024 threads * 16 B
#define FS 393216         // fp32 table offset (floats) = 96*CHB/4

__global__ void prep_kernel(const float* __restrict__ W_ih1,
                            const float* __restrict__ W_hh1,
                            const float* __restrict__ b_ih1,
                            const float* __restrict__ b_hh1,
                            const float* __restrict__ W_ih2,
                            const float* __restrict__ W_hh2,
                            const float* __restrict__ b_ih2,
                            const float* __restrict__ b_hh2,
                            void* __restrict__ ws) {
    const int stride = gridDim.x * blockDim.x;
    const int idx = blockIdx.x * blockDim.x + threadIdx.x;
    _Float16* wh = (_Float16*)ws;
    float* wf = (float*)ws;
    // chunk ch (0..95) covers k = 8*ch..8*ch+7 for all 1024 gate-rows.
    // k<256: W_hh1 | k<512: W_ih2 | else W_hh2.
    for (int e = idx; e < NCH * 8192; e += stride) {
        int ch = e >> 13, rem = e & 8191, row = rem >> 3, i = rem & 7;
        int k = (ch << 3) + i;
        float v;
        if (k < 256)      v = W_hh1[row * 256 + k];
        else if (k < 512) v = W_ih2[row * 256 + (k - 256)];
        else              v = W_hh2[row * 256 + (k - 512)];
        wh[e] = (_Float16)v;
    }
    for (int j = idx; j < 1024; j += stride) {
        wf[FS + j]        = W_ih1[j * 2 + 0];
        wf[FS + 1024 + j] = W_ih1[j * 2 + 1];
        wf[FS + 2048 + j] = b_ih1[j] + b_hh1[j];
        wf[FS + 3072 + j] = b_ih2[j] + b_hh2[j];
    }
}

__device__ __forceinline__ float sig_(float v) {
    return 1.f / (1.f + __expf(-v));
}
__device__ __forceinline__ float tanh_(float v) {
    return 1.f - 2.f / (__expf(2.f * v) + 1.f);
}
__device__ __forceinline__ float fdot2_(vh2 a, vh2 b, float c) {
#if __has_builtin(__builtin_amdgcn_fdot2)
    return __builtin_amdgcn_fdot2(a, b, c, false);
#else
    return c + (float)a.x * (float)b.x + (float)a.y * (float)b.y;
#endif
}

__global__ __launch_bounds__(NT, 4) void lstm_kernel(
    const float* __restrict__ x,      // (512, 256, 2)
    const void* __restrict__ ws,
    const float* __restrict__ W_lin,  // (2, 256)
    const float* __restrict__ b_lin,  // (2,)
    float* __restrict__ out)          // (512, 256, 2)
{
    __shared__ float gbuf[2][1024];        // gate preacts [batch][gate-row]
    __shared__ _Float16 hl1[2][2][256];    // h1 [parity][batch][unit]
    __shared__ _Float16 hl2[2][2][256];    // h2

    const int tid = threadIdx.x;
    const int j = tid;                     // owned gate-row (j = gate*256+unit)
    const int u = tid & 255, bu = (tid >> 8) & 1;
    const int b0 = blockIdx.x * 2;
    const char* wstream = (const char*)ws;
    const float* wf = (const float*)ws;

    const float wx0 = wf[FS + j], wx1 = wf[FS + 1024 + j];
    const float bj1 = wf[FS + 2048 + j], bj2 = wf[FS + 3072 + j];

    // y-head: waves 0..3 -> (batch ob, output oo); lane covers 4 units
    const int lane = tid & 63, wv = tid >> 6;
    const int ob = (wv >> 1) & 1, oo = wv & 1;
    const float wl0 = W_lin[oo * 256 + 4 * lane + 0];
    const float wl1 = W_lin[oo * 256 + 4 * lane + 1];
    const float wl2 = W_lin[oo * 256 + 4 * lane + 2];
    const float wl3 = W_lin[oo * 256 + 4 * lane + 3];
    const float blin = b_lin[oo];

    for (int i = tid; i < 2 * 2 * 256; i += NT) {
        ((_Float16*)hl1)[i] = (_Float16)0.f;
        ((_Float16*)hl2)[i] = (_Float16)0.f;
    }

    float c1 = 0.f, c2 = 0.f;
    vf2 xv0 = *(const vf2*)(x + (size_t)(b0 + 0) * 512);
    vf2 xv1 = *(const vf2*)(x + (size_t)(b0 + 1) * 512);

    const int t16 = tid * 16;
    int sp = 0;                            // uniform stream byte offset
    float acc0, acc1;

    auto loadc = [&](vh8& dst) {
        dst = *(const vh8*)(wstream + sp + t16);
        sp += CHB;
        if (sp == NCH * CHB) sp = 0;
    };
    auto usec = [&](const vh8 w, const _Float16 (*hp)[256], int k0) {
        vh2 w0 = {w[0], w[1]}, w1 = {w[2], w[3]};
        vh2 w2 = {w[4], w[5]}, w3 = {w[6], w[7]};
        vh8 ha = *(const vh8*)&hp[0][k0];
        vh8 hb = *(const vh8*)&hp[1][k0];
        vh2 a0 = {ha[0], ha[1]}, a1 = {ha[2], ha[3]};
        vh2 a2 = {ha[4], ha[5]}, a3 = {ha[6], ha[7]};
        vh2 e0 = {hb[0], hb[1]}, e1 = {hb[2], hb[3]};
        vh2 e2 = {hb[4], hb[5]}, e3 = {hb[6], hb[7]};
        acc0 = fdot2_(w0, a0, acc0); acc0 = fdot2_(w1, a1, acc0);
        acc0 = fdot2_(w2, a2, acc0); acc0 = fdot2_(w3, a3, acc0);
        acc1 = fdot2_(w0, e0, acc1); acc1 = fdot2_(w1, e1, acc1);
        acc1 = fdot2_(w2, e2, acc1); acc1 = fdot2_(w3, e3, acc1);
    };

    vh8 bA, bB, bC, bD;
    loadc(bA); loadc(bB); loadc(bC); loadc(bD);
    __syncthreads();

    auto gemm32 = [&](const _Float16 (*hp)[256]) {
        #pragma unroll 1
        for (int q = 0; q < 32; q += 4) {
            usec(bA, hp, 8 * q);      loadc(bA);
            usec(bB, hp, 8 * q + 8);  loadc(bB);
            usec(bC, hp, 8 * q + 16); loadc(bC);
            usec(bD, hp, 8 * q + 24); loadc(bD);
        }
    };

    #pragma unroll 1
    for (int t = 0; t < TSTEPS; ++t) {
        const int p = t & 1, pm = p ^ 1;

        // ---- layer 1 gates: b1 + Wih1*x_t + Whh1*h1(t-1) ----
        acc0 = bj1 + wx0 * xv0.x + wx1 * xv0.y;
        acc1 = bj1 + wx0 * xv1.x + wx1 * xv1.y;
        gemm32(hl1[pm]);
        gbuf[0][j] = acc0; gbuf[1][j] = acc1;
        __syncthreads();

        // ---- layer 1 cell update (threads 0..511: unit u, batch bu) ----
        if (tid < 512) {
            float gi = sig_(gbuf[bu][u]);
            float gf = sig_(gbuf[bu][256 + u]);
            float gg = tanh_(gbuf[bu][512 + u]);
            float go = sig_(gbuf[bu][768 + u]);
            c1 = gf * c1 + gi * gg;
            hl1[p][bu][u] = (_Float16)(go * tanh_(c1));
        }
        __syncthreads();

        // ---- layer 2 gates: b2 + Wih2*h1(t) + Whh2*h2(t-1) ----
        acc0 = bj2; acc1 = bj2;
        gemm32(hl1[p]);
        gemm32(hl2[pm]);
        gbuf[0][j] = acc0; gbuf[1][j] = acc1;
        __syncthreads();

        // ---- layer 2 cell update ----
        if (tid < 512) {
            float gi = sig_(gbuf[bu][u]);
            float gf = sig_(gbuf[bu][256 + u]);
            float gg = tanh_(gbuf[bu][512 + u]);
            float go = sig_(gbuf[bu][768 + u]);
            c2 = gf * c2 + gi * gg;
            hl2[p][bu][u] = (_Float16)(go * tanh_(c2));
        }
        __syncthreads();

        // ---- y = h2 @ W_lin.T + b_lin (waves 0..3) ----
        if (wv < 4) {
            vh4 hv = *(const vh4*)&hl2[p][ob][4 * lane];
            float s = (float)hv.x * wl0 + (float)hv.y * wl1
                    + (float)hv.z * wl2 + (float)hv.w * wl3;
            #pragma unroll
            for (int m = 32; m >= 1; m >>= 1) s += __shfl_xor(s, m, 64);
            if (lane == 0)
                out[(size_t)(b0 + ob) * 512 + t * 2 + oo] = s + blin;
        }

        // prefetch x for t+1 (wraps harmlessly at the end)
        const int tn = (t + 1) & (TSTEPS - 1);
        xv0 = *(const vf2*)(x + (size_t)(b0 + 0) * 512 + tn * 2);
        xv1 = *(const vf2*)(x + (size_t)(b0 + 1) * 512 + tn * 2);
    }
}

extern "C" void kernel_launch(void* const* d_in, const int* in_sizes, int n_in,
                              void* d_out, int out_size, void* d_ws, size_t ws_size,
                              hipStream_t stream) {
    const float* x     = (const float*)d_in[0];
    const float* W_ih1 = (const float*)d_in[1];
    const float* W_hh1 = (const float*)d_in[2];
    const float* b_ih1 = (const float*)d_in[3];
    const float* b_hh1 = (const float*)d_in[4];
    const float* W_ih2 = (const float*)d_in[5];
    const float* W_hh2 = (const float*)d_in[6];
    const float* b_ih2 = (const float*)d_in[7];
    const float* b_hh2 = (const float*)d_in[8];
    const float* W_lin = (const float*)d_in[9];
    const float* b_lin = (const float*)d_in[10];
    float* out = (float*)d_out;

    prep_kernel<<<256, 256, 0, stream>>>(W_ih1, W_hh1, b_ih1, b_hh1,
                                         W_ih2, W_hh2, b_ih2, b_hh2, d_ws);
    lstm_kernel<<<256, NT, 0, stream>>>(x, d_ws, W_lin, b_lin, out);
}